// Round 2
// baseline (1075.905 us; speedup 1.0000x reference)
//
#include <hip/hip_runtime.h>
#include <hip/hip_bf16.h>
#include <stdint.h>

#define N_NODES 50000
#define N_EDGES 1600000
#define IN_F 256
#define OUT_F 64
#define N_HEADS 8
#define ALPHA 0.2f
#define GAT_EPS 1e-16f
#define NB_SCAN 49  // ceil(50000/1024)

typedef __bf16 bf16x8 __attribute__((ext_vector_type(8)));
typedef float f32x4 __attribute__((ext_vector_type(4)));

// ---------------- K0: W [8][256][64] f32 -> WT_hi/WT_lo [8][64][256] bf16 ----------------
__global__ void wt_kernel(const float* __restrict__ W, __bf16* __restrict__ WT_hi,
                          __bf16* __restrict__ WT_lo) {
    int i = blockIdx.x * 256 + threadIdx.x;
    if (i < N_HEADS * IN_F * OUT_F) {
        int h = i >> 14;          // /16384
        int rem = i & 16383;
        int k = rem >> 6;         // /64
        int d = rem & 63;
        float w = W[i];
        __bf16 hi = (__bf16)w;
        __bf16 lo = (__bf16)(w - (float)hi);
        WT_hi[h * 16384 + d * 256 + k] = hi;
        WT_lo[h * 16384 + d * 256 + k] = lo;
    }
}

// ---------------- K1: GEMM  Wh[n][h][d] = sum_k h[n][k] * W[h][k][d]
// Split-bf16 (hi+lo) MFMA: acc = Ah*Bh + Al*Bh + Ah*Bl  (f32-accurate).
// Fused epilogue: s_src[n][h], s_dst[n][h] from f32 accumulators.
__global__ __launch_bounds__(256) void gemm_kernel(
        const float* __restrict__ hmat, const __bf16* __restrict__ WT_hi,
        const __bf16* __restrict__ WT_lo, const float* __restrict__ avec,
        __bf16* __restrict__ Wh, float* __restrict__ s_src, float* __restrict__ s_dst) {
    // A_hi [0,32K) A_lo [32K,64K) B_hi [64K,96K) B_lo [96K,128K)
    __shared__ __align__(16) unsigned char smem[131072];
    const int row0 = blockIdx.x * 64;
    const int t = threadIdx.x;
    const int lane = t & 63;
    const int wid = t >> 6;

    // stage A tile: 64 rows x 256 k, f32 -> (hi,lo) bf16, XOR-swizzled rows (512B rows)
    #pragma unroll
    for (int i = 0; i < 8; ++i) {
        int u = t + i * 256;          // unit of 8 elems
        int r = u >> 5;
        int kb = (u & 31) * 8;
        int gr = row0 + r;
        float4 f0, f1;
        if (gr < N_NODES) {
            f0 = *(const float4*)(hmat + (size_t)gr * IN_F + kb);
            f1 = *(const float4*)(hmat + (size_t)gr * IN_F + kb + 4);
        } else {
            f0 = make_float4(0.f, 0.f, 0.f, 0.f); f1 = f0;
        }
        float fv[8] = {f0.x, f0.y, f0.z, f0.w, f1.x, f1.y, f1.z, f1.w};
        bf16x8 vh, vl;
        #pragma unroll
        for (int j = 0; j < 8; ++j) {
            __bf16 hi = (__bf16)fv[j];
            vh[j] = hi;
            vl[j] = (__bf16)(fv[j] - (float)hi);
        }
        int addr = (r * 512 + kb * 2) ^ ((r & 7) << 4);
        *(bf16x8*)(smem + addr) = vh;
        *(bf16x8*)(smem + 32768 + addr) = vl;
    }

    f32x4 acc[4];
    const int cbase = lane & 15;
    const int koff = (lane >> 4) * 8;
    const int arow = (wid * 16) + cbase;      // A fragment row within tile
    const int rloc = wid * 16 + (lane >> 4) * 4;

    for (int head = 0; head < N_HEADS; ++head) {
        __syncthreads();   // previous head's B reads done (also covers A staging)
        // stage B: WT[head] = [64 d][256 k] bf16 hi+lo, same swizzle
        const __bf16* Bh = WT_hi + head * (OUT_F * IN_F);
        const __bf16* Bl = WT_lo + head * (OUT_F * IN_F);
        #pragma unroll
        for (int i = 0; i < 8; ++i) {
            int u = t + i * 256;
            int r = u >> 5;
            int kb = (u & 31) * 8;
            int addr = (r * 512 + kb * 2) ^ ((r & 7) << 4);
            *(bf16x8*)(smem + 65536 + addr) = *(const bf16x8*)(Bh + r * IN_F + kb);
            *(bf16x8*)(smem + 98304 + addr) = *(const bf16x8*)(Bl + r * IN_F + kb);
        }
        __syncthreads();

        acc[0] = 0.f; acc[1] = 0.f; acc[2] = 0.f; acc[3] = 0.f;
        #pragma unroll
        for (int kk = 0; kk < 8; ++kk) {
            int kbase = kk * 32 + koff;
            int aaddr = (arow * 512 + kbase * 2) ^ ((arow & 7) << 4);
            bf16x8 ah = *(const bf16x8*)(smem + aaddr);
            bf16x8 al = *(const bf16x8*)(smem + 32768 + aaddr);
            #pragma unroll
            for (int nf = 0; nf < 4; ++nf) {
                int bcol = nf * 16 + cbase;
                int baddr = (bcol * 512 + kbase * 2) ^ ((bcol & 7) << 4);
                bf16x8 bh = *(const bf16x8*)(smem + 65536 + baddr);
                bf16x8 bl = *(const bf16x8*)(smem + 98304 + baddr);
                acc[nf] = __builtin_amdgcn_mfma_f32_16x16x32_bf16(ah, bh, acc[nf], 0, 0, 0);
                acc[nf] = __builtin_amdgcn_mfma_f32_16x16x32_bf16(al, bh, acc[nf], 0, 0, 0);
                acc[nf] = __builtin_amdgcn_mfma_f32_16x16x32_bf16(ah, bl, acc[nf], 0, 0, 0);
            }
        }

        // write Wh (bf16). C/D: col = lane&15 (+16*nf), row = (lane>>4)*4 + r
        #pragma unroll
        for (int nf = 0; nf < 4; ++nf) {
            #pragma unroll
            for (int r = 0; r < 4; ++r) {
                int grow = row0 + rloc + r;
                if (grow < N_NODES)
                    Wh[(size_t)grow * 512 + head * 64 + nf * 16 + cbase] = (__bf16)acc[nf][r];
            }
        }

        // fused s_src / s_dst from f32 accumulators
        float p1[4] = {0.f, 0.f, 0.f, 0.f}, p2[4] = {0.f, 0.f, 0.f, 0.f};
        #pragma unroll
        for (int nf = 0; nf < 4; ++nf) {
            float as = avec[head * 128 + nf * 16 + cbase];
            float ad = avec[head * 128 + 64 + nf * 16 + cbase];
            #pragma unroll
            for (int r = 0; r < 4; ++r) { p1[r] += acc[nf][r] * as; p2[r] += acc[nf][r] * ad; }
        }
        #pragma unroll
        for (int m = 1; m < 16; m <<= 1) {
            #pragma unroll
            for (int r = 0; r < 4; ++r) {
                p1[r] += __shfl_xor(p1[r], m);
                p2[r] += __shfl_xor(p2[r], m);
            }
        }
        if ((lane & 15) == 0) {
            #pragma unroll
            for (int r = 0; r < 4; ++r) {
                int grow = row0 + rloc + r;
                if (grow < N_NODES) {
                    s_src[grow * 8 + head] = p1[r];
                    s_dst[grow * 8 + head] = p2[r];
                }
            }
        }
    }
}

// ---------------- K3: per-row edge histogram ----------------
__global__ void hist_kernel(const int* __restrict__ row, int* __restrict__ counts) {
    int i = blockIdx.x * 256 + threadIdx.x;
    if (i < N_EDGES) atomicAdd(&counts[row[i]], 1);
}

// ---------------- K4: 3-kernel exclusive scan over counts ----------------
__global__ __launch_bounds__(1024) void scan1(const int* __restrict__ counts,
        int* __restrict__ offs, int* __restrict__ bsums) {
    __shared__ int wsum[16];
    int t = threadIdx.x;
    int g = blockIdx.x * 1024 + t;
    int v = (g < N_NODES) ? counts[g] : 0;
    int lane = t & 63, wv = t >> 6;
    int incl = v;
    #pragma unroll
    for (int off = 1; off < 64; off <<= 1) {
        int u = __shfl_up(incl, off);
        if (lane >= off) incl += u;
    }
    if (lane == 63) wsum[wv] = incl;
    __syncthreads();
    if (t < 16) {
        int x = wsum[t];
        #pragma unroll
        for (int off = 1; off < 16; off <<= 1) {
            int u = __shfl_up(x, off);
            if (t >= off) x += u;
        }
        wsum[t] = x; // inclusive over wave sums
    }
    __syncthreads();
    int wexcl = (wv == 0) ? 0 : wsum[wv - 1];
    if (g < N_NODES) offs[g] = wexcl + incl - v;   // block-local exclusive
    if (t == 1023) bsums[blockIdx.x] = wsum[15];
}

__global__ void scan2(int* __restrict__ bsums, int* __restrict__ offs) {
    int t = threadIdx.x; // 64 threads, 1 wave
    int v = (t < NB_SCAN) ? bsums[t] : 0;
    int incl = v;
    #pragma unroll
    for (int off = 1; off < 64; off <<= 1) {
        int u = __shfl_up(incl, off);
        if (t >= off) incl += u;
    }
    if (t < NB_SCAN) bsums[t] = incl - v;   // exclusive
    if (t == NB_SCAN - 1) offs[N_NODES] = incl;  // grand total
}

__global__ __launch_bounds__(1024) void scan3(int* __restrict__ offs,
        const int* __restrict__ bsums) {
    int g = blockIdx.x * 1024 + threadIdx.x;
    if (g < N_NODES) offs[g] += bsums[blockIdx.x];
}

// ---------------- K5: scatter cols into row-sorted order ----------------
__global__ void scatter_kernel(const int* __restrict__ row, const int* __restrict__ col,
        const int* __restrict__ offs, int* __restrict__ cursor, int* __restrict__ scol) {
    int i = blockIdx.x * 256 + threadIdx.x;
    if (i < N_EDGES) {
        int r = row[i];
        int pos = offs[r] + atomicAdd(&cursor[r], 1);
        scol[pos] = col[i];
    }
}

// ---------------- K6: per-(row,head) wave softmax aggregation ----------------
__global__ __launch_bounds__(256) void agg_kernel(const int* __restrict__ offs,
        const int* __restrict__ scol, const float* __restrict__ s_src,
        const float* __restrict__ s_dst, const __bf16* __restrict__ Wh,
        float* __restrict__ out) {
    int wg = blockIdx.x * 4 + (threadIdx.x >> 6);
    if (wg >= N_NODES * N_HEADS) return;
    int lane = threadIdx.x & 63;
    int row = wg >> 3, head = wg & 7;
    int beg = offs[row], end = offs[row + 1];
    int ne = end - beg;
    float acc = 0.f;
    if (ne > 0) {
        float ss = s_src[wg];
        const __bf16* whb = Wh + head * 64 + lane;
        if (ne <= 64) {
            int c = 0; float e = 0.f;
            bool valid = lane < ne;
            if (valid) {
                c = scol[beg + lane];
                float x = ss + s_dst[c * 8 + head];
                e = x > 0.f ? x : ALPHA * x;
            }
            float rs = e;
            #pragma unroll
            for (int m = 1; m < 64; m <<= 1) rs += __shfl_xor(rs, m);
            float p = valid ? __expf(e - rs) : 0.f;
            float dn = p;
            #pragma unroll
            for (int m = 1; m < 64; m <<= 1) dn += __shfl_xor(dn, m);
            float w = p * (1.f / (dn + GAT_EPS));
            for (int j = 0; j < ne; ++j) {
                float aj = __shfl(w, j);
                int cj = __shfl(c, j);
                acc += aj * (float)whb[(size_t)cj * 512];
            }
        } else {
            // rare fallback: ne > 64, chunked with recompute
            float esum = 0.f;
            for (int base = 0; base < ne; base += 64) {
                int idx = base + lane;
                if (idx < ne) {
                    int cc = scol[beg + idx];
                    float x = ss + s_dst[cc * 8 + head];
                    esum += (x > 0.f ? x : ALPHA * x);
                }
            }
            float rs = esum;
            #pragma unroll
            for (int m = 1; m < 64; m <<= 1) rs += __shfl_xor(rs, m);
            float psum = 0.f;
            for (int base = 0; base < ne; base += 64) {
                int idx = base + lane;
                if (idx < ne) {
                    int cc = scol[beg + idx];
                    float x = ss + s_dst[cc * 8 + head];
                    float e = x > 0.f ? x : ALPHA * x;
                    psum += __expf(e - rs);
                }
            }
            float dn = psum;
            #pragma unroll
            for (int m = 1; m < 64; m <<= 1) dn += __shfl_xor(dn, m);
            float inv = 1.f / (dn + GAT_EPS);
            for (int base = 0; base < ne; base += 64) {
                int idx = base + lane;
                int c = 0; float w = 0.f;
                if (idx < ne) {
                    c = scol[beg + idx];
                    float x = ss + s_dst[c * 8 + head];
                    float e = x > 0.f ? x : ALPHA * x;
                    w = __expf(e - rs) * inv;
                }
                int lim = min(64, ne - base);
                for (int j = 0; j < lim; ++j) {
                    float aj = __shfl(w, j);
                    int cj = __shfl(c, j);
                    acc += aj * (float)whb[(size_t)cj * 512];
                }
            }
        }
    }
    out[(size_t)row * 512 + head * 64 + lane] = acc;
}

// ---------------- launch ----------------
extern "C" void kernel_launch(void* const* d_in, const int* in_sizes, int n_in,
                              void* d_out, int out_size, void* d_ws, size_t ws_size,
                              hipStream_t stream) {
    const float* hmat = (const float*)d_in[0];
    const float* W    = (const float*)d_in[1];
    const float* avec = (const float*)d_in[2];
    const int*   ei   = (const int*)d_in[3];
    const int* row = ei;
    const int* col = ei + N_EDGES;

    char* ws = (char*)d_ws;
    __bf16* WT_hi  = (__bf16*)(ws + 0);            //   256 KB
    __bf16* WT_lo  = (__bf16*)(ws + 262144);       //   256 KB
    __bf16* Wh     = (__bf16*)(ws + 524288);       //  51.2 MB
    float*  s_src  = (float*)(ws + 51724288);      //   1.6 MB
    float*  s_dst  = (float*)(ws + 53324288);      //   1.6 MB
    int*    counts = (int*)(ws + 54924288);        //   200 KB
    int*    offs   = (int*)(ws + 55124288);        //   200 KB + 4
    int*    cursor = (int*)(ws + 55324544);        //   200 KB
    int*    scol   = (int*)(ws + 55524544);        //   6.4 MB
    int*    bsums  = (int*)(ws + 61924544);        //   256 B
    float*  out    = (float*)d_out;

    hipMemsetAsync(counts, 0, N_NODES * 4, stream);
    hipMemsetAsync(cursor, 0, N_NODES * 4, stream);

    wt_kernel<<<512, 256, 0, stream>>>(W, WT_hi, WT_lo);
    hist_kernel<<<(N_EDGES + 255) / 256, 256, 0, stream>>>(row, counts);
    gemm_kernel<<<(N_NODES + 63) / 64, 256, 0, stream>>>(hmat, WT_hi, WT_lo, avec, Wh, s_src, s_dst);
    scan1<<<NB_SCAN, 1024, 0, stream>>>(counts, offs, bsums);
    scan2<<<1, 64, 0, stream>>>(bsums, offs);
    scan3<<<NB_SCAN, 1024, 0, stream>>>(offs, bsums);
    scatter_kernel<<<(N_EDGES + 255) / 256, 256, 0, stream>>>(row, col, offs, cursor, scol);
    agg_kernel<<<(N_NODES * N_HEADS + 3) / 4, 256, 0, stream>>>(offs, scol, s_src, s_dst, Wh, out);
}

// Round 3
// 672.389 us; speedup vs baseline: 1.6001x; 1.6001x over previous
//
#include <hip/hip_runtime.h>
#include <hip/hip_bf16.h>
#include <stdint.h>

#define N_NODES 50000
#define N_EDGES 1600000
#define IN_F 256
#define OUT_F 64
#define N_HEADS 8
#define ALPHA 0.2f
#define GAT_EPS 1e-16f
#define NB_SCAN 49  // ceil(50000/1024)

typedef __bf16 bf16x8 __attribute__((ext_vector_type(8)));
typedef float f32x4 __attribute__((ext_vector_type(4)));

// ---------------- K0: W [8][256][64] f32 -> WT_hi/WT_lo [8][64][256] bf16 ----------------
__global__ void wt_kernel(const float* __restrict__ W, __bf16* __restrict__ WT_hi,
                          __bf16* __restrict__ WT_lo) {
    int i = blockIdx.x * 256 + threadIdx.x;
    if (i < N_HEADS * IN_F * OUT_F) {
        int h = i >> 14;          // /16384
        int rem = i & 16383;
        int k = rem >> 6;         // /64
        int d = rem & 63;
        float w = W[i];
        __bf16 hi = (__bf16)w;
        __bf16 lo = (__bf16)(w - (float)hi);
        WT_hi[h * 16384 + d * 256 + k] = hi;
        WT_lo[h * 16384 + d * 256 + k] = lo;
    }
}

// ---------------- K1: GEMM  Wh[n][h][d] = sum_k h[n][k] * W[h][k][d]
// Split-bf16 (hi+lo) MFMA: acc = Ah*Bh + Al*Bh + Ah*Bl  (f32-accurate).
// Fused epilogue: s_src[n][h], s_dst[n][h] from f32 accumulators.
__global__ __launch_bounds__(256) void gemm_kernel(
        const float* __restrict__ hmat, const __bf16* __restrict__ WT_hi,
        const __bf16* __restrict__ WT_lo, const float* __restrict__ avec,
        __bf16* __restrict__ Wh, float* __restrict__ s_src, float* __restrict__ s_dst) {
    // A_hi [0,32K) A_lo [32K,64K) B_hi [64K,96K) B_lo [96K,128K)
    __shared__ __align__(16) unsigned char smem[131072];
    const int row0 = blockIdx.x * 64;
    const int t = threadIdx.x;
    const int lane = t & 63;
    const int wid = t >> 6;

    // stage A tile: 64 rows x 256 k, f32 -> (hi,lo) bf16, XOR-swizzled rows (512B rows)
    #pragma unroll
    for (int i = 0; i < 8; ++i) {
        int u = t + i * 256;          // unit of 8 elems
        int r = u >> 5;
        int kb = (u & 31) * 8;
        int gr = row0 + r;
        float4 f0, f1;
        if (gr < N_NODES) {
            f0 = *(const float4*)(hmat + (size_t)gr * IN_F + kb);
            f1 = *(const float4*)(hmat + (size_t)gr * IN_F + kb + 4);
        } else {
            f0 = make_float4(0.f, 0.f, 0.f, 0.f); f1 = f0;
        }
        float fv[8] = {f0.x, f0.y, f0.z, f0.w, f1.x, f1.y, f1.z, f1.w};
        bf16x8 vh, vl;
        #pragma unroll
        for (int j = 0; j < 8; ++j) {
            __bf16 hi = (__bf16)fv[j];
            vh[j] = hi;
            vl[j] = (__bf16)(fv[j] - (float)hi);
        }
        int addr = (r * 512 + kb * 2) ^ ((r & 7) << 4);
        *(bf16x8*)(smem + addr) = vh;
        *(bf16x8*)(smem + 32768 + addr) = vl;
    }

    f32x4 acc[4];
    const int cbase = lane & 15;
    const int koff = (lane >> 4) * 8;
    const int arow = (wid * 16) + cbase;      // A fragment row within tile
    const int rloc = wid * 16 + (lane >> 4) * 4;

    for (int head = 0; head < N_HEADS; ++head) {
        __syncthreads();   // previous head's B reads done (also covers A staging)
        // stage B: WT[head] = [64 d][256 k] bf16 hi+lo, same swizzle
        const __bf16* Bh = WT_hi + head * (OUT_F * IN_F);
        const __bf16* Bl = WT_lo + head * (OUT_F * IN_F);
        #pragma unroll
        for (int i = 0; i < 8; ++i) {
            int u = t + i * 256;
            int r = u >> 5;
            int kb = (u & 31) * 8;
            int addr = (r * 512 + kb * 2) ^ ((r & 7) << 4);
            *(bf16x8*)(smem + 65536 + addr) = *(const bf16x8*)(Bh + r * IN_F + kb);
            *(bf16x8*)(smem + 98304 + addr) = *(const bf16x8*)(Bl + r * IN_F + kb);
        }
        __syncthreads();

        acc[0] = 0.f; acc[1] = 0.f; acc[2] = 0.f; acc[3] = 0.f;
        #pragma unroll
        for (int kk = 0; kk < 8; ++kk) {
            int kbase = kk * 32 + koff;
            int aaddr = (arow * 512 + kbase * 2) ^ ((arow & 7) << 4);
            bf16x8 ah = *(const bf16x8*)(smem + aaddr);
            bf16x8 al = *(const bf16x8*)(smem + 32768 + aaddr);
            #pragma unroll
            for (int nf = 0; nf < 4; ++nf) {
                int bcol = nf * 16 + cbase;
                int baddr = (bcol * 512 + kbase * 2) ^ ((bcol & 7) << 4);
                bf16x8 bh = *(const bf16x8*)(smem + 65536 + baddr);
                bf16x8 bl = *(const bf16x8*)(smem + 98304 + baddr);
                acc[nf] = __builtin_amdgcn_mfma_f32_16x16x32_bf16(ah, bh, acc[nf], 0, 0, 0);
                acc[nf] = __builtin_amdgcn_mfma_f32_16x16x32_bf16(al, bh, acc[nf], 0, 0, 0);
                acc[nf] = __builtin_amdgcn_mfma_f32_16x16x32_bf16(ah, bl, acc[nf], 0, 0, 0);
            }
        }

        // write Wh (bf16). C/D: col = lane&15 (+16*nf), row = (lane>>4)*4 + r
        #pragma unroll
        for (int nf = 0; nf < 4; ++nf) {
            #pragma unroll
            for (int r = 0; r < 4; ++r) {
                int grow = row0 + rloc + r;
                if (grow < N_NODES)
                    Wh[(size_t)grow * 512 + head * 64 + nf * 16 + cbase] = (__bf16)acc[nf][r];
            }
        }

        // fused s_src / s_dst from f32 accumulators
        float p1[4] = {0.f, 0.f, 0.f, 0.f}, p2[4] = {0.f, 0.f, 0.f, 0.f};
        #pragma unroll
        for (int nf = 0; nf < 4; ++nf) {
            float as = avec[head * 128 + nf * 16 + cbase];
            float ad = avec[head * 128 + 64 + nf * 16 + cbase];
            #pragma unroll
            for (int r = 0; r < 4; ++r) { p1[r] += acc[nf][r] * as; p2[r] += acc[nf][r] * ad; }
        }
        #pragma unroll
        for (int m = 1; m < 16; m <<= 1) {
            #pragma unroll
            for (int r = 0; r < 4; ++r) {
                p1[r] += __shfl_xor(p1[r], m);
                p2[r] += __shfl_xor(p2[r], m);
            }
        }
        if ((lane & 15) == 0) {
            #pragma unroll
            for (int r = 0; r < 4; ++r) {
                int grow = row0 + rloc + r;
                if (grow < N_NODES) {
                    s_src[grow * 8 + head] = p1[r];
                    s_dst[grow * 8 + head] = p2[r];
                }
            }
        }
    }
}

// ---------------- K3: per-row edge histogram ----------------
__global__ void hist_kernel(const int* __restrict__ row, int* __restrict__ counts) {
    int i = blockIdx.x * 256 + threadIdx.x;
    if (i < N_EDGES) atomicAdd(&counts[row[i]], 1);
}

// ---------------- K4: 3-kernel exclusive scan over counts ----------------
__global__ __launch_bounds__(1024) void scan1(const int* __restrict__ counts,
        int* __restrict__ offs, int* __restrict__ bsums) {
    __shared__ int wsum[16];
    int t = threadIdx.x;
    int g = blockIdx.x * 1024 + t;
    int v = (g < N_NODES) ? counts[g] : 0;
    int lane = t & 63, wv = t >> 6;
    int incl = v;
    #pragma unroll
    for (int off = 1; off < 64; off <<= 1) {
        int u = __shfl_up(incl, off);
        if (lane >= off) incl += u;
    }
    if (lane == 63) wsum[wv] = incl;
    __syncthreads();
    if (t < 16) {
        int x = wsum[t];
        #pragma unroll
        for (int off = 1; off < 16; off <<= 1) {
            int u = __shfl_up(x, off);
            if (t >= off) x += u;
        }
        wsum[t] = x; // inclusive over wave sums
    }
    __syncthreads();
    int wexcl = (wv == 0) ? 0 : wsum[wv - 1];
    if (g < N_NODES) offs[g] = wexcl + incl - v;   // block-local exclusive
    if (t == 1023) bsums[blockIdx.x] = wsum[15];
}

__global__ void scan2(int* __restrict__ bsums, int* __restrict__ offs) {
    int t = threadIdx.x; // 64 threads, 1 wave
    int v = (t < NB_SCAN) ? bsums[t] : 0;
    int incl = v;
    #pragma unroll
    for (int off = 1; off < 64; off <<= 1) {
        int u = __shfl_up(incl, off);
        if (t >= off) incl += u;
    }
    if (t < NB_SCAN) bsums[t] = incl - v;   // exclusive
    if (t == NB_SCAN - 1) offs[N_NODES] = incl;  // grand total
}

__global__ __launch_bounds__(1024) void scan3(int* __restrict__ offs,
        const int* __restrict__ bsums) {
    int g = blockIdx.x * 1024 + threadIdx.x;
    if (g < N_NODES) offs[g] += bsums[blockIdx.x];
}

// ---------------- K5: scatter cols into row-sorted order ----------------
__global__ void scatter_kernel(const int* __restrict__ row, const int* __restrict__ col,
        const int* __restrict__ offs, int* __restrict__ cursor, int* __restrict__ scol) {
    int i = blockIdx.x * 256 + threadIdx.x;
    if (i < N_EDGES) {
        int r = row[i];
        int pos = offs[r] + atomicAdd(&cursor[r], 1);
        scol[pos] = col[i];
    }
}

// ---------------- K6: per-(row,head) wave softmax aggregation (v2: 8-edge-wide gather) ----
__global__ __launch_bounds__(256) void agg_kernel(const int* __restrict__ offs,
        const int* __restrict__ scol, const float* __restrict__ s_src,
        const float* __restrict__ s_dst, const __bf16* __restrict__ Wh,
        float* __restrict__ out) {
    __shared__ float w_lds[4][64];
    __shared__ int   c_lds[4][64];
    int wv = threadIdx.x >> 6;
    int wg = blockIdx.x * 4 + wv;
    if (wg >= N_NODES * N_HEADS) return;
    int lane = threadIdx.x & 63;
    int row = wg >> 3, head = wg & 7;
    int beg = offs[row], end = offs[row + 1];
    int ne = end - beg;

    const int sub = lane >> 3;        // edge slot 0..7 within an iteration
    const int dq  = (lane & 7) * 8;   // dim block: 8 dims per lane
    const __bf16* whbase = Wh + head * 64 + dq;

    float acc[8] = {0.f, 0.f, 0.f, 0.f, 0.f, 0.f, 0.f, 0.f};

    if (ne > 0) {
        float ss = s_src[wg];
        if (ne <= 64) {
            // single-chunk: weights in one pass
            int c = 0; float e = 0.f;
            bool valid = lane < ne;
            if (valid) {
                c = scol[beg + lane];
                float x = ss + s_dst[c * 8 + head];
                e = x > 0.f ? x : ALPHA * x;
            }
            float rs = valid ? e : 0.f;
            #pragma unroll
            for (int m = 1; m < 64; m <<= 1) rs += __shfl_xor(rs, m);
            float p = valid ? __expf(e - rs) : 0.f;
            float dn = p;
            #pragma unroll
            for (int m = 1; m < 64; m <<= 1) dn += __shfl_xor(dn, m);
            float wgt = p * (1.f / (dn + GAT_EPS));
            w_lds[wv][lane] = wgt;     // 0 for invalid lanes
            c_lds[wv][lane] = c;       // 0 for invalid lanes
            // gather: 8 edges per iteration, 16B per lane
            for (int j0 = 0; j0 < ne; j0 += 8) {
                int j = j0 + sub;                  // may spill past ne-1 -> w=0
                float wj = w_lds[wv][j];
                int   cj = c_lds[wv][j];
                bf16x8 v = *(const bf16x8*)(whbase + (size_t)cj * 512);
                #pragma unroll
                for (int k = 0; k < 8; ++k) acc[k] += wj * (float)v[k];
            }
        } else {
            // rare: ne > 64, multi-chunk with exact reference math
            float esum = 0.f;
            for (int base = 0; base < ne; base += 64) {
                int idx = base + lane;
                if (idx < ne) {
                    int cc = scol[beg + idx];
                    float x = ss + s_dst[cc * 8 + head];
                    esum += (x > 0.f ? x : ALPHA * x);
                }
            }
            float rs = esum;
            #pragma unroll
            for (int m = 1; m < 64; m <<= 1) rs += __shfl_xor(rs, m);
            float psum = 0.f;
            for (int base = 0; base < ne; base += 64) {
                int idx = base + lane;
                if (idx < ne) {
                    int cc = scol[beg + idx];
                    float x = ss + s_dst[cc * 8 + head];
                    float e = x > 0.f ? x : ALPHA * x;
                    psum += __expf(e - rs);
                }
            }
            float dn = psum;
            #pragma unroll
            for (int m = 1; m < 64; m <<= 1) dn += __shfl_xor(dn, m);
            float inv = 1.f / (dn + GAT_EPS);
            for (int base = 0; base < ne; base += 64) {
                int idx = base + lane;
                float wgt = 0.f; int c = 0;
                if (idx < ne) {
                    c = scol[beg + idx];
                    float x = ss + s_dst[c * 8 + head];
                    float e = x > 0.f ? x : ALPHA * x;
                    wgt = __expf(e - rs) * inv;
                }
                w_lds[wv][lane] = wgt;
                c_lds[wv][lane] = c;
                int lim = min(64, ne - base);
                for (int j0 = 0; j0 < lim; j0 += 8) {
                    int j = j0 + sub;
                    float wj = w_lds[wv][j];
                    int   cj = c_lds[wv][j];
                    bf16x8 v = *(const bf16x8*)(whbase + (size_t)cj * 512);
                    #pragma unroll
                    for (int k = 0; k < 8; ++k) acc[k] += wj * (float)v[k];
                }
            }
        }
    }

    // reduce partial sums across the 8 edge-slots (stride-8 lane groups)
    #pragma unroll
    for (int m = 8; m < 64; m <<= 1) {
        #pragma unroll
        for (int k = 0; k < 8; ++k) acc[k] += __shfl_xor(acc[k], m);
    }
    if (sub == 0) {
        float* op = out + (size_t)row * 512 + head * 64 + dq;
        float4 o0 = make_float4(acc[0], acc[1], acc[2], acc[3]);
        float4 o1 = make_float4(acc[4], acc[5], acc[6], acc[7]);
        *(float4*)op = o0;
        *(float4*)(op + 4) = o1;
    }
}

// ---------------- launch ----------------
extern "C" void kernel_launch(void* const* d_in, const int* in_sizes, int n_in,
                              void* d_out, int out_size, void* d_ws, size_t ws_size,
                              hipStream_t stream) {
    const float* hmat = (const float*)d_in[0];
    const float* W    = (const float*)d_in[1];
    const float* avec = (const float*)d_in[2];
    const int*   ei   = (const int*)d_in[3];
    const int* row = ei;
    const int* col = ei + N_EDGES;

    char* ws = (char*)d_ws;
    __bf16* WT_hi  = (__bf16*)(ws + 0);            //   256 KB
    __bf16* WT_lo  = (__bf16*)(ws + 262144);       //   256 KB
    __bf16* Wh     = (__bf16*)(ws + 524288);       //  51.2 MB
    float*  s_src  = (float*)(ws + 51724288);      //   1.6 MB
    float*  s_dst  = (float*)(ws + 53324288);      //   1.6 MB
    int*    counts = (int*)(ws + 54924288);        //   200 KB
    int*    offs   = (int*)(ws + 55124288);        //   200 KB + 4
    int*    cursor = (int*)(ws + 55324544);        //   200 KB
    int*    scol   = (int*)(ws + 55524544);        //   6.4 MB
    int*    bsums  = (int*)(ws + 61924544);        //   256 B
    float*  out    = (float*)d_out;

    hipMemsetAsync(counts, 0, N_NODES * 4, stream);
    hipMemsetAsync(cursor, 0, N_NODES * 4, stream);

    wt_kernel<<<512, 256, 0, stream>>>(W, WT_hi, WT_lo);
    hist_kernel<<<(N_EDGES + 255) / 256, 256, 0, stream>>>(row, counts);
    gemm_kernel<<<(N_NODES + 63) / 64, 256, 0, stream>>>(hmat, WT_hi, WT_lo, avec, Wh, s_src, s_dst);
    scan1<<<NB_SCAN, 1024, 0, stream>>>(counts, offs, bsums);
    scan2<<<1, 64, 0, stream>>>(bsums, offs);
    scan3<<<NB_SCAN, 1024, 0, stream>>>(offs, bsums);
    scatter_kernel<<<(N_EDGES + 255) / 256, 256, 0, stream>>>(row, col, offs, cursor, scol);
    agg_kernel<<<(N_NODES * N_HEADS + 3) / 4, 256, 0, stream>>>(offs, scol, s_src, s_dst, Wh, out);
}